// Round 1
// baseline (548.581 us; speedup 1.0000x reference)
//
#include <hip/hip_runtime.h>

// out[b, I[e]] += inputs[b, J[e]] * W3[e] * velocity[J[e]]; out += bias
// R2: per-edge atomics = 204.8MB atomic-path traffic (bound).
// R4: bucket build + high-occupancy gather -> 161.7us; k_build dominates.
// R5: nt stores FALSIFIED (WRITE rose to 53MB) - reverted.
// R6: two-pass counting sort, dense writes -> 159us. finesort = 196 blocks
//     (0.77/CU, chip mostly idle) + edges round-trip (12.8MB) + 3 total
//     LDS-atomic histogram passes over E.
// R7: DELETE finesort. Gather filters instead of sorts: 4 blocks per coarse
//     256-row bucket, each owns a 64-row quadrant, ballot-compacts its ~25%
//     of the bucket's records, accumulates via hardware ds_add_f32 into a
//     64x65 LDS tile. part re-read x4 is LLC-resident. k_partition now does
//     ONE LDS-atomic pass (rank = count atomicAdd, records stashed in
//     static-indexed register arrays). Pipeline: prep, hist, scan,
//     partition, gather (5 launches).

#define BATCH 64
#define ROWS_PC 256           // rows per coarse bucket (pass-1 bin)
#define QROWS 64              // rows per gather block (quadrant)
#define PCHUNK 2048           // edges per pass-1 block

typedef unsigned long long ull;

// ---- K1: transpose inputs [B,N] -> in_T [N,B]; zero coarse histogram ----
__global__ void k_prep(const float* __restrict__ in, float* __restrict__ in_T,
                       int* __restrict__ coarse_hist, int NC, int N) {
    const int gid = blockIdx.x * 256 + threadIdx.x;
    if (gid < NC) coarse_hist[gid] = 0;

    __shared__ float tile[64 * 65];
    const int n0 = blockIdx.x * 64;
    const int t  = threadIdx.x;
    const int x  = t & 63;
    const int r  = t >> 6;
    for (int b = r; b < BATCH; b += 4) {
        float v = 0.f;
        if (n0 + x < N) v = in[(size_t)b * N + n0 + x];
        tile[x * 65 + b] = v;
    }
    __syncthreads();
    for (int xr = r; xr < 64; xr += 4) {
        if (n0 + xr < N) in_T[(size_t)(n0 + xr) * BATCH + x] = tile[xr * 65 + x];
    }
}

// ---- K2: coarse histogram (LDS-aggregated) ----
__global__ void k_hist(const int* __restrict__ I, int* __restrict__ coarse_hist, int E) {
    __shared__ int h[256];
    const int t = threadIdx.x;
    h[t] = 0;
    __syncthreads();
    const int e0 = blockIdx.x * PCHUNK;
    int e1 = e0 + PCHUNK; if (e1 > E) e1 = E;
    for (int e = e0 + t; e < e1; e += 256) atomicAdd(&h[I[e] >> 8], 1);
    __syncthreads();
    if (h[t]) atomicAdd(&coarse_hist[t], h[t]);
}

// ---- K3: exclusive scan of NC (<=256) coarse counts; init cursors ----
__global__ void k_scan(const int* __restrict__ coarse_hist, int* __restrict__ coarse_base,
                       int* __restrict__ gcursor, int NC) {
    __shared__ int sh[256];
    const int t = threadIdx.x;
    const int v = (t < NC) ? coarse_hist[t] : 0;
    sh[t] = v;
    __syncthreads();
    for (int off = 1; off < 256; off <<= 1) {
        const int u = (t >= off) ? sh[t - off] : 0;
        __syncthreads();
        sh[t] += u;
        __syncthreads();
    }
    if (t < NC) { coarse_base[t] = sh[t] - v; gcursor[t] = sh[t] - v; }
    if (t == NC - 1) coarse_base[NC] = sh[t];   // = E
}

// ---- K4: pass-1 partition into coarse buckets (dense run reservations) ----
// record u64: hi32 = bits(w), lo32 = (i & 255) << 16 | j
// Single LDS-atomic pass: the counting atomicAdd IS the rank; records are
// stashed in statically-indexed register arrays (no scratch, rule #20).
__global__ void __launch_bounds__(256) k_partition(
        const int* __restrict__ I, const int* __restrict__ J,
        const float* __restrict__ W3, const float* __restrict__ velocity,
        int* __restrict__ gcursor, ull* __restrict__ part, int E) {
    __shared__ int hist[256];
    __shared__ int base[256];
    const int t = threadIdx.x;
    hist[t] = 0;
    __syncthreads();
    const int e0 = blockIdx.x * PCHUNK;
    int e1 = e0 + PCHUNK; if (e1 > E) e1 = E;

    ull  rec[8];
    int  cb[8];
    int  rk[8];
    bool ok[8];
    #pragma unroll
    for (int u = 0; u < 8; ++u) {
        const int e = e0 + u * 256 + t;
        ok[u] = (e < e1);
        cb[u] = 0; rk[u] = 0; rec[u] = 0ull;
        if (ok[u]) {
            const int   i = I[e];
            const int   j = J[e];
            const float w = W3[e] * velocity[j];
            cb[u] = i >> 8;
            rk[u] = atomicAdd(&hist[cb[u]], 1);
            rec[u] = ((ull)__float_as_uint(w) << 32)
                   | ((ull)((unsigned)(i & 255) << 16) | (unsigned)j);
        }
    }
    __syncthreads();
    const int cnt = hist[t];
    base[t] = cnt ? atomicAdd(&gcursor[t], cnt) : 0;  // one reservation per (block,bucket)
    __syncthreads();
    #pragma unroll
    for (int u = 0; u < 8; ++u) {
        if (ok[u]) part[(size_t)base[cb[u]] + rk[u]] = rec[u];
    }
}

// ---- K5: gather-with-filter. Block = one 64-row quadrant of a coarse ----
// bucket; 8 waves scan the bucket's records, ballot-compact the ~25% that
// hit this quadrant, accumulate via ds_add_f32 into a 64x65 LDS tile.
__global__ void __launch_bounds__(512) k_gather(
        const float* __restrict__ in_T, const ull* __restrict__ part,
        const int* __restrict__ coarse_base, const float* __restrict__ bias,
        float* __restrict__ out, int N) {
    __shared__ float tile[64 * 65];
    const int t    = threadIdx.x;
    const int lane = t & 63;
    const int w    = t >> 6;                 // wave 0..7
    const int c    = blockIdx.x >> 2;        // coarse bucket
    const int q    = blockIdx.x & 3;         // 64-row quadrant within bucket

    for (int idx = t; idx < 64 * 65; idx += 512) tile[idx] = 0.f;
    __syncthreads();

    const int beg = coarse_base[c];
    const int end = coarse_base[c + 1];

    for (int base = beg + w * 64; base < end; base += 512) {
        int cc = end - base; if (cc > 64) cc = 64;
        ull rec = 0ull;
        if (lane < cc) rec = part[base + lane];
        const int rlo = (int)(unsigned)(rec & 0xffffffffu);
        const int rhi = (int)(unsigned)(rec >> 32);
        // quadrant id = top 2 bits of the 8-bit local row
        const bool mine = (lane < cc) && ((((unsigned)rlo >> 22) & 3u) == (unsigned)q);
        ull mask = __ballot(mine);
        while (mask) {
            float v[8], wv[8]; int li[8];
            #pragma unroll
            for (int u = 0; u < 8; ++u) {
                unsigned ij = 0u, wb = 0u;
                if (mask) {                           // wave-uniform branch
                    const int k = (int)__ffsll(mask) - 1;
                    mask &= (mask - 1);
                    ij = (unsigned)__shfl(rlo, k);
                    wb = (unsigned)__shfl(rhi, k);
                }
                wv[u] = __uint_as_float(wb);          // 0.0 for padding slots
                li[u] = (int)((ij >> 16) & 63u);
                const int j = (int)(ij & 0xffffu);
                v[u] = in_T[j * BATCH + lane];        // 8 independent loads in flight
            }
            #pragma unroll
            for (int u = 0; u < 8; ++u) {
                unsafeAtomicAdd(&tile[li[u] * 65 + lane], v[u] * wv[u]);  // ds_add_f32
            }
        }
    }
    __syncthreads();

    // epilogue: rows [n0, n0+64) -> out[b*N+n] + bias, coalesced per b
    const int n0  = c * ROWS_PC + q * QROWS;
    const int row = t & 63;
    const int bq  = t >> 6;
    const int n = n0 + row;
    if (n < N) {
        const float bv = bias[n];
        for (int b = bq; b < BATCH; b += 8)
            out[(size_t)b * N + n] = tile[row * 65 + b] + bv;
    }
}

// ---- fallback path (ws too small or N doesn't fit u16): direct atomics ----
__global__ void k_edge_scatter_direct(const float* __restrict__ in,
                                      const float* __restrict__ W3,
                                      const float* __restrict__ velocity,
                                      const int* __restrict__ I,
                                      const int* __restrict__ J,
                                      float* __restrict__ out, int N, int E) {
    const int lane = threadIdx.x & 63;
    const long wave   = (long)blockIdx.x * (blockDim.x >> 6) + (threadIdx.x >> 6);
    const long nwaves = (long)gridDim.x * (blockDim.x >> 6);
    for (long base = wave * 64; base < E; base += nwaves * 64) {
        const long e = base + lane;
        int iv = 0, jv = 0; float wvv = 0.f;
        if (e < E) { iv = I[e]; jv = J[e]; wvv = W3[e] * velocity[jv]; }
        const int cnt = (int)((E - base) < 64 ? (E - base) : 64);
        for (int k = 0; k < cnt; ++k) {
            const int   ii = __shfl(iv, k);
            const int   jj = __shfl(jv, k);
            const float wvx = __shfl(wvv, k);
            const float val = in[(size_t)lane * N + jj] * wvx;
            atomicAdd(&out[(size_t)lane * N + ii], val);
        }
    }
}

__global__ void k_add_bias(const float* __restrict__ bias, float* __restrict__ out, int N, int total) {
    int idx = blockIdx.x * blockDim.x + threadIdx.x;
    if (idx < total) out[idx] += bias[idx % N];
}

extern "C" void kernel_launch(void* const* d_in, const int* in_sizes, int n_in,
                              void* d_out, int out_size, void* d_ws, size_t ws_size,
                              hipStream_t stream) {
    const float* inputs   = (const float*)d_in[0];
    const float* W3       = (const float*)d_in[1];
    const float* bias     = (const float*)d_in[2];
    const float* velocity = (const float*)d_in[3];
    const int*   I        = (const int*)d_in[4];
    const int*   J        = (const int*)d_in[5];
    const int E = in_sizes[1];
    const int N = in_sizes[3];
    float* out = (float*)d_out;

    const size_t mat_elems = (size_t)N * BATCH;
    const int NC   = (N + ROWS_PC - 1) / ROWS_PC;   // coarse buckets
    const int nb_n = (N + 63) / 64;
    const int nb_e = (E + PCHUNK - 1) / PCHUNK;
    const int nb_g = NC * 4;                        // one block per 64-row quadrant

    // ws: in_T | part | coarse_hist | coarse_base | gcursor
    const size_t need = mat_elems * sizeof(float)
                      + (size_t)E * sizeof(ull)
                      + (size_t)(NC + (NC + 1) + NC) * sizeof(int);

    if (ws_size >= need && N <= 65535 && NC <= 256) {
        float* in_T        = (float*)d_ws;
        ull*   part        = (ull*)(in_T + mat_elems);
        int*   coarse_hist = (int*)(part + E);
        int*   coarse_base = coarse_hist + NC;
        int*   gcursor     = coarse_base + NC + 1;

        k_prep     <<<nb_n, 256, 0, stream>>>(inputs, in_T, coarse_hist, NC, N);
        k_hist     <<<nb_e, 256, 0, stream>>>(I, coarse_hist, E);
        k_scan     <<<1,    256, 0, stream>>>(coarse_hist, coarse_base, gcursor, NC);
        k_partition<<<nb_e, 256, 0, stream>>>(I, J, W3, velocity, gcursor, part, E);
        k_gather   <<<nb_g, 512, 0, stream>>>(in_T, part, coarse_base, bias, out, N);
    } else {
        hipMemsetAsync(out, 0, (size_t)out_size * sizeof(float), stream);
        const int waves_needed   = (E + 63) / 64;
        const int scatter_blocks = (waves_needed + 3) / 4;
        k_edge_scatter_direct<<<scatter_blocks, 256, 0, stream>>>(inputs, W3, velocity, I, J, out, N, E);
        k_add_bias<<<(out_size + 255) / 256, 256, 0, stream>>>(bias, out, N, out_size);
    }
}

// Round 2
// 468.067 us; speedup vs baseline: 1.1720x; 1.1720x over previous
//
#include <hip/hip_runtime.h>

// out[b, I[e]] += inputs[b, J[e]] * W3[e] * velocity[J[e]]; out += bias
// R2: per-edge atomics = 204.8MB atomic-path traffic (bound).
// R4: bucket build + high-occupancy gather -> 161.7us; k_build dominates.
// R5: nt stores FALSIFIED (WRITE rose to 53MB) - reverted.
// R6: two-pass counting sort, dense writes -> 159us. finesort starved
//     (196 blocks) + edges round-trip + 3 LDS-atomic passes over E.
// R7: fused filter-gather via ballot + dynamic-lane shuffle chain: PASSED but
//     445us. VGPR_Count=16 => full scratch spill (dynamic __shfl(.,k) chain
//     inside if(mask) defeated regalloc); FETCH 88MB = scratch traffic;
//     VALUBusy 3.4% = latency-bound on spills. Filter idea correct,
//     implementation falsified.
// R8: same fused filter-gather, but compaction through LDS instead of
//     shuffles: phase A ballot-compacts this quadrant's records into an LDS
//     buffer (static lane-0 leader, popcount rank, ds_write_b64); phase B
//     processes them R6-style with uniform-address ds_read_b64 broadcast +
//     8 independent in_T row loads + ds_add_f32 tile accumulate. No dynamic
//     shuffles, all arrays statically indexed. 33KB LDS -> 4 blocks/CU.

#define BATCH 64
#define ROWS_PC 256           // rows per coarse bucket (pass-1 bin)
#define QROWS 64              // rows per gather block (quadrant)
#define PCHUNK 2048           // edges per pass-1 block
#define GCHUNK 2048           // records per gather compaction chunk

typedef unsigned long long ull;

// ---- K1: transpose inputs [B,N] -> in_T [N,B]; zero coarse histogram ----
__global__ void k_prep(const float* __restrict__ in, float* __restrict__ in_T,
                       int* __restrict__ coarse_hist, int NC, int N) {
    const int gid = blockIdx.x * 256 + threadIdx.x;
    if (gid < NC) coarse_hist[gid] = 0;

    __shared__ float tile[64 * 65];
    const int n0 = blockIdx.x * 64;
    const int t  = threadIdx.x;
    const int x  = t & 63;
    const int r  = t >> 6;
    for (int b = r; b < BATCH; b += 4) {
        float v = 0.f;
        if (n0 + x < N) v = in[(size_t)b * N + n0 + x];
        tile[x * 65 + b] = v;
    }
    __syncthreads();
    for (int xr = r; xr < 64; xr += 4) {
        if (n0 + xr < N) in_T[(size_t)(n0 + xr) * BATCH + x] = tile[xr * 65 + x];
    }
}

// ---- K2: coarse histogram (LDS-aggregated) ----
__global__ void k_hist(const int* __restrict__ I, int* __restrict__ coarse_hist, int E) {
    __shared__ int h[256];
    const int t = threadIdx.x;
    h[t] = 0;
    __syncthreads();
    const int e0 = blockIdx.x * PCHUNK;
    int e1 = e0 + PCHUNK; if (e1 > E) e1 = E;
    for (int e = e0 + t; e < e1; e += 256) atomicAdd(&h[I[e] >> 8], 1);
    __syncthreads();
    if (h[t]) atomicAdd(&coarse_hist[t], h[t]);
}

// ---- K3: exclusive scan of NC (<=256) coarse counts; init cursors ----
__global__ void k_scan(const int* __restrict__ coarse_hist, int* __restrict__ coarse_base,
                       int* __restrict__ gcursor, int NC) {
    __shared__ int sh[256];
    const int t = threadIdx.x;
    const int v = (t < NC) ? coarse_hist[t] : 0;
    sh[t] = v;
    __syncthreads();
    for (int off = 1; off < 256; off <<= 1) {
        const int u = (t >= off) ? sh[t - off] : 0;
        __syncthreads();
        sh[t] += u;
        __syncthreads();
    }
    if (t < NC) { coarse_base[t] = sh[t] - v; gcursor[t] = sh[t] - v; }
    if (t == NC - 1) coarse_base[NC] = sh[t];   // = E
}

// ---- K4: pass-1 partition into coarse buckets (dense run reservations) ----
// record u64: hi32 = bits(w), lo32 = (i & 255) << 16 | j
// Single LDS-atomic pass: the counting atomicAdd IS the rank; records are
// stashed in statically-indexed register arrays (no scratch, rule #20).
__global__ void __launch_bounds__(256) k_partition(
        const int* __restrict__ I, const int* __restrict__ J,
        const float* __restrict__ W3, const float* __restrict__ velocity,
        int* __restrict__ gcursor, ull* __restrict__ part, int E) {
    __shared__ int hist[256];
    __shared__ int base[256];
    const int t = threadIdx.x;
    hist[t] = 0;
    __syncthreads();
    const int e0 = blockIdx.x * PCHUNK;
    int e1 = e0 + PCHUNK; if (e1 > E) e1 = E;

    ull  rec[8];
    int  cb[8];
    int  rk[8];
    bool ok[8];
    #pragma unroll
    for (int u = 0; u < 8; ++u) {
        const int e = e0 + u * 256 + t;
        ok[u] = (e < e1);
        cb[u] = 0; rk[u] = 0; rec[u] = 0ull;
        if (ok[u]) {
            const int   i = I[e];
            const int   j = J[e];
            const float w = W3[e] * velocity[j];
            cb[u] = i >> 8;
            rk[u] = atomicAdd(&hist[cb[u]], 1);
            rec[u] = ((ull)__float_as_uint(w) << 32)
                   | ((ull)((unsigned)(i & 255) << 16) | (unsigned)j);
        }
    }
    __syncthreads();
    const int cnt = hist[t];
    base[t] = cnt ? atomicAdd(&gcursor[t], cnt) : 0;  // one reservation per (block,bucket)
    __syncthreads();
    #pragma unroll
    for (int u = 0; u < 8; ++u) {
        if (ok[u]) part[(size_t)base[cb[u]] + rk[u]] = rec[u];
    }
}

// ---- K5: fused filter-gather. Block = one 64-row quadrant of a coarse ----
// bucket. Phase A: ballot-compact this quadrant's records into LDS (static
// lane-0 leader + popcount rank). Phase B: uniform ds_read_b64 broadcast,
// 8 in_T row loads in flight, ds_add_f32 into 64x65 tile.
__global__ void __launch_bounds__(512) k_gather(
        const float* __restrict__ in_T, const ull* __restrict__ part,
        const int* __restrict__ coarse_base, const float* __restrict__ bias,
        float* __restrict__ out, int N) {
    __shared__ float tile[64 * 65];
    __shared__ ull   lds_rec[GCHUNK + 8];
    __shared__ int   cnt;
    const int t    = threadIdx.x;
    const int lane = t & 63;
    const int w    = t >> 6;                 // wave 0..7
    const int c    = blockIdx.x >> 2;        // coarse bucket
    const unsigned q = blockIdx.x & 3;       // 64-row quadrant within bucket

    for (int idx = t; idx < 64 * 65; idx += 512) tile[idx] = 0.f;

    const int beg = coarse_base[c];
    const int end = coarse_base[c + 1];

    for (int chunk_beg = beg; chunk_beg < end; chunk_beg += GCHUNK) {
        int chunk_end = chunk_beg + GCHUNK; if (chunk_end > end) chunk_end = end;
        __syncthreads();                     // tile init / prev phase B done
        if (t == 0) cnt = 0;
        __syncthreads();

        // ---- phase A: compact my quadrant's records into lds_rec ----
        for (int e0 = chunk_beg; e0 < chunk_end; e0 += 512) {
            const int e = e0 + t;
            ull rec = 0ull; bool mine = false;
            if (e < chunk_end) {
                rec  = part[e];
                mine = ((((unsigned)rec) >> 22) & 3u) == q;
            }
            const ull mask = __ballot(mine);
            int wbase = 0;
            if (lane == 0) wbase = atomicAdd(&cnt, (int)__popcll(mask));
            wbase = __shfl(wbase, 0);        // static lane index
            if (mine) {
                const int rank = (int)__popcll(mask & ((1ull << lane) - 1ull));
                lds_rec[wbase + rank] = rec;
            }
        }
        __syncthreads();

        const int R  = cnt;
        const int Rp = (R + 7) & ~7;         // pad to multiple of 8
        if (t < Rp - R) lds_rec[R + t] = 0ull;   // zero rec: adds 0 to row 0
        __syncthreads();

        // ---- phase B: process records, 8 loads in flight per wave ----
        for (int r0 = w * 8; r0 < Rp; r0 += 64) {
            float v[8], wv[8]; int li[8];
            #pragma unroll
            for (int u = 0; u < 8; ++u) {
                const ull rec = lds_rec[r0 + u];     // uniform addr -> broadcast
                const unsigned lo = (unsigned)rec;
                wv[u] = __uint_as_float((unsigned)(rec >> 32));
                li[u] = (int)((lo >> 16) & 63u);
                const int j = (int)(lo & 0xffffu);
                v[u] = in_T[j * BATCH + lane];       // 8 independent 256B loads
            }
            #pragma unroll
            for (int u = 0; u < 8; ++u) {
                unsafeAtomicAdd(&tile[li[u] * 65 + lane], v[u] * wv[u]);  // ds_add_f32
            }
        }
    }
    __syncthreads();

    // epilogue: rows [n0, n0+64) -> out[b*N+n] + bias, coalesced per b
    const int n0  = c * ROWS_PC + (int)q * QROWS;
    const int row = t & 63;
    const int bq  = t >> 6;
    const int n = n0 + row;
    if (n < N) {
        const float bv = bias[n];
        for (int b = bq; b < BATCH; b += 8)
            out[(size_t)b * N + n] = tile[row * 65 + b] + bv;
    }
}

// ---- fallback path (ws too small or N doesn't fit u16): direct atomics ----
__global__ void k_edge_scatter_direct(const float* __restrict__ in,
                                      const float* __restrict__ W3,
                                      const float* __restrict__ velocity,
                                      const int* __restrict__ I,
                                      const int* __restrict__ J,
                                      float* __restrict__ out, int N, int E) {
    const int lane = threadIdx.x & 63;
    const long wave   = (long)blockIdx.x * (blockDim.x >> 6) + (threadIdx.x >> 6);
    const long nwaves = (long)gridDim.x * (blockDim.x >> 6);
    for (long base = wave * 64; base < E; base += nwaves * 64) {
        const long e = base + lane;
        int iv = 0, jv = 0; float wvv = 0.f;
        if (e < E) { iv = I[e]; jv = J[e]; wvv = W3[e] * velocity[jv]; }
        const int cnt = (int)((E - base) < 64 ? (E - base) : 64);
        for (int k = 0; k < cnt; ++k) {
            const int   ii = __shfl(iv, k);
            const int   jj = __shfl(jv, k);
            const float wvx = __shfl(wvv, k);
            const float val = in[(size_t)lane * N + jj] * wvx;
            atomicAdd(&out[(size_t)lane * N + ii], val);
        }
    }
}

__global__ void k_add_bias(const float* __restrict__ bias, float* __restrict__ out, int N, int total) {
    int idx = blockIdx.x * blockDim.x + threadIdx.x;
    if (idx < total) out[idx] += bias[idx % N];
}

extern "C" void kernel_launch(void* const* d_in, const int* in_sizes, int n_in,
                              void* d_out, int out_size, void* d_ws, size_t ws_size,
                              hipStream_t stream) {
    const float* inputs   = (const float*)d_in[0];
    const float* W3       = (const float*)d_in[1];
    const float* bias     = (const float*)d_in[2];
    const float* velocity = (const float*)d_in[3];
    const int*   I        = (const int*)d_in[4];
    const int*   J        = (const int*)d_in[5];
    const int E = in_sizes[1];
    const int N = in_sizes[3];
    float* out = (float*)d_out;

    const size_t mat_elems = (size_t)N * BATCH;
    const int NC   = (N + ROWS_PC - 1) / ROWS_PC;   // coarse buckets
    const int nb_n = (N + 63) / 64;
    const int nb_e = (E + PCHUNK - 1) / PCHUNK;
    const int nb_g = NC * 4;                        // one block per 64-row quadrant

    // ws: in_T | part | coarse_hist | coarse_base | gcursor
    const size_t need = mat_elems * sizeof(float)
                      + (size_t)E * sizeof(ull)
                      + (size_t)(NC + (NC + 1) + NC) * sizeof(int);

    if (ws_size >= need && N <= 65535 && NC <= 256) {
        float* in_T        = (float*)d_ws;
        ull*   part        = (ull*)(in_T + mat_elems);
        int*   coarse_hist = (int*)(part + E);
        int*   coarse_base = coarse_hist + NC;
        int*   gcursor     = coarse_base + NC + 1;

        k_prep     <<<nb_n, 256, 0, stream>>>(inputs, in_T, coarse_hist, NC, N);
        k_hist     <<<nb_e, 256, 0, stream>>>(I, coarse_hist, E);
        k_scan     <<<1,    256, 0, stream>>>(coarse_hist, coarse_base, gcursor, NC);
        k_partition<<<nb_e, 256, 0, stream>>>(I, J, W3, velocity, gcursor, part, E);
        k_gather   <<<nb_g, 512, 0, stream>>>(in_T, part, coarse_base, bias, out, N);
    } else {
        hipMemsetAsync(out, 0, (size_t)out_size * sizeof(float), stream);
        const int waves_needed   = (E + 63) / 64;
        const int scatter_blocks = (waves_needed + 3) / 4;
        k_edge_scatter_direct<<<scatter_blocks, 256, 0, stream>>>(inputs, W3, velocity, I, J, out, N, E);
        k_add_bias<<<(out_size + 255) / 256, 256, 0, stream>>>(bias, out, N, out_size);
    }
}

// Round 3
// 466.316 us; speedup vs baseline: 1.1764x; 1.0038x over previous
//
#include <hip/hip_runtime.h>

// out[b, I[e]] += inputs[b, J[e]] * W3[e] * velocity[J[e]]; out += bias
// R2: per-edge atomics = 204.8MB atomic-path traffic (bound).
// R4: bucket build + high-occupancy gather -> 161.7us; k_build dominates.
// R5: nt stores FALSIFIED (WRITE rose to 53MB) - reverted.
// R6: two-pass counting sort, dense writes -> 159us. finesort starved
//     (196 blocks) + edges round-trip + 3 LDS-atomic passes over E.
// R7: fused filter-gather, shuffle compaction: 445us. Blamed spills.
// R8: LDS compaction + broadcast phase B: 357us. FALSIFIES spill theory:
//     VGPR 16->24, FETCH ~87MB in BOTH R7/R8 (intrinsic, not scratch),
//     duration ~same. Common factor = unsafeAtomicAdd on the LDS tile
//     (specified for GLOBAL fp atomics; on shared it doesn't lower to
//     ds_add_f32 -> CAS/flat path, 51.2M lane-atomics = the ~350us).
// R9: identical structure, tile update via standard atomicAdd(shared float)
//     = native ds_add_f32 (~6cyc/wave-op, row*65+lane = free 2-way alias).
//     Clean A/B on the atomic lowering.

#define BATCH 64
#define ROWS_PC 256           // rows per coarse bucket (pass-1 bin)
#define QROWS 64              // rows per gather block (quadrant)
#define PCHUNK 2048           // edges per pass-1 block
#define GCHUNK 2048           // records per gather compaction chunk

typedef unsigned long long ull;

// ---- K1: transpose inputs [B,N] -> in_T [N,B]; zero coarse histogram ----
__global__ void k_prep(const float* __restrict__ in, float* __restrict__ in_T,
                       int* __restrict__ coarse_hist, int NC, int N) {
    const int gid = blockIdx.x * 256 + threadIdx.x;
    if (gid < NC) coarse_hist[gid] = 0;

    __shared__ float tile[64 * 65];
    const int n0 = blockIdx.x * 64;
    const int t  = threadIdx.x;
    const int x  = t & 63;
    const int r  = t >> 6;
    for (int b = r; b < BATCH; b += 4) {
        float v = 0.f;
        if (n0 + x < N) v = in[(size_t)b * N + n0 + x];
        tile[x * 65 + b] = v;
    }
    __syncthreads();
    for (int xr = r; xr < 64; xr += 4) {
        if (n0 + xr < N) in_T[(size_t)(n0 + xr) * BATCH + x] = tile[xr * 65 + x];
    }
}

// ---- K2: coarse histogram (LDS-aggregated) ----
__global__ void k_hist(const int* __restrict__ I, int* __restrict__ coarse_hist, int E) {
    __shared__ int h[256];
    const int t = threadIdx.x;
    h[t] = 0;
    __syncthreads();
    const int e0 = blockIdx.x * PCHUNK;
    int e1 = e0 + PCHUNK; if (e1 > E) e1 = E;
    for (int e = e0 + t; e < e1; e += 256) atomicAdd(&h[I[e] >> 8], 1);
    __syncthreads();
    if (h[t]) atomicAdd(&coarse_hist[t], h[t]);
}

// ---- K3: exclusive scan of NC (<=256) coarse counts; init cursors ----
__global__ void k_scan(const int* __restrict__ coarse_hist, int* __restrict__ coarse_base,
                       int* __restrict__ gcursor, int NC) {
    __shared__ int sh[256];
    const int t = threadIdx.x;
    const int v = (t < NC) ? coarse_hist[t] : 0;
    sh[t] = v;
    __syncthreads();
    for (int off = 1; off < 256; off <<= 1) {
        const int u = (t >= off) ? sh[t - off] : 0;
        __syncthreads();
        sh[t] += u;
        __syncthreads();
    }
    if (t < NC) { coarse_base[t] = sh[t] - v; gcursor[t] = sh[t] - v; }
    if (t == NC - 1) coarse_base[NC] = sh[t];   // = E
}

// ---- K4: pass-1 partition into coarse buckets (dense run reservations) ----
// record u64: hi32 = bits(w), lo32 = (i & 255) << 16 | j
__global__ void __launch_bounds__(256) k_partition(
        const int* __restrict__ I, const int* __restrict__ J,
        const float* __restrict__ W3, const float* __restrict__ velocity,
        int* __restrict__ gcursor, ull* __restrict__ part, int E) {
    __shared__ int hist[256];
    __shared__ int base[256];
    const int t = threadIdx.x;
    hist[t] = 0;
    __syncthreads();
    const int e0 = blockIdx.x * PCHUNK;
    int e1 = e0 + PCHUNK; if (e1 > E) e1 = E;

    ull  rec[8];
    int  cb[8];
    int  rk[8];
    bool ok[8];
    #pragma unroll
    for (int u = 0; u < 8; ++u) {
        const int e = e0 + u * 256 + t;
        ok[u] = (e < e1);
        cb[u] = 0; rk[u] = 0; rec[u] = 0ull;
        if (ok[u]) {
            const int   i = I[e];
            const int   j = J[e];
            const float w = W3[e] * velocity[j];
            cb[u] = i >> 8;
            rk[u] = atomicAdd(&hist[cb[u]], 1);
            rec[u] = ((ull)__float_as_uint(w) << 32)
                   | ((ull)((unsigned)(i & 255) << 16) | (unsigned)j);
        }
    }
    __syncthreads();
    const int cnt = hist[t];
    base[t] = cnt ? atomicAdd(&gcursor[t], cnt) : 0;  // one reservation per (block,bucket)
    __syncthreads();
    #pragma unroll
    for (int u = 0; u < 8; ++u) {
        if (ok[u]) part[(size_t)base[cb[u]] + rk[u]] = rec[u];
    }
}

// ---- K5: fused filter-gather. Block = one 64-row quadrant of a coarse ----
// bucket. Phase A: ballot-compact this quadrant's records into LDS. Phase B:
// uniform ds_read_b64 broadcast, 8 in_T loads in flight, native ds_add_f32.
__global__ void __launch_bounds__(512) k_gather(
        const float* __restrict__ in_T, const ull* __restrict__ part,
        const int* __restrict__ coarse_base, const float* __restrict__ bias,
        float* __restrict__ out, int N) {
    __shared__ float tile[64 * 65];
    __shared__ ull   lds_rec[GCHUNK + 8];
    __shared__ int   cnt;
    const int t    = threadIdx.x;
    const int lane = t & 63;
    const int w    = t >> 6;                 // wave 0..7
    const int c    = blockIdx.x >> 2;        // coarse bucket
    const unsigned q = blockIdx.x & 3;       // 64-row quadrant within bucket

    for (int idx = t; idx < 64 * 65; idx += 512) tile[idx] = 0.f;

    const int beg = coarse_base[c];
    const int end = coarse_base[c + 1];

    for (int chunk_beg = beg; chunk_beg < end; chunk_beg += GCHUNK) {
        int chunk_end = chunk_beg + GCHUNK; if (chunk_end > end) chunk_end = end;
        __syncthreads();                     // tile init / prev phase B done
        if (t == 0) cnt = 0;
        __syncthreads();

        // ---- phase A: compact my quadrant's records into lds_rec ----
        for (int e0 = chunk_beg; e0 < chunk_end; e0 += 512) {
            const int e = e0 + t;
            ull rec = 0ull; bool mine = false;
            if (e < chunk_end) {
                rec  = part[e];
                mine = ((((unsigned)rec) >> 22) & 3u) == q;
            }
            const ull mask = __ballot(mine);
            int wbase = 0;
            if (lane == 0) wbase = atomicAdd(&cnt, (int)__popcll(mask));
            wbase = __shfl(wbase, 0);        // static lane index
            if (mine) {
                const int rank = (int)__popcll(mask & ((1ull << lane) - 1ull));
                lds_rec[wbase + rank] = rec;
            }
        }
        __syncthreads();

        const int R  = cnt;
        const int Rp = (R + 7) & ~7;         // pad to multiple of 8
        if (t < Rp - R) lds_rec[R + t] = 0ull;   // zero rec: adds 0 to row 0
        __syncthreads();

        // ---- phase B: process records, 8 loads in flight per wave ----
        for (int r0 = w * 8; r0 < Rp; r0 += 64) {
            float v[8], wv[8]; int li[8];
            #pragma unroll
            for (int u = 0; u < 8; ++u) {
                const ull rec = lds_rec[r0 + u];     // uniform addr -> broadcast
                const unsigned lo = (unsigned)rec;
                wv[u] = __uint_as_float((unsigned)(rec >> 32));
                li[u] = (int)((lo >> 16) & 63u);
                const int j = (int)(lo & 0xffffu);
                v[u] = in_T[j * BATCH + lane];       // 8 independent 256B loads
            }
            #pragma unroll
            for (int u = 0; u < 8; ++u) {
                atomicAdd(&tile[li[u] * 65 + lane], v[u] * wv[u]);  // native ds_add_f32
            }
        }
    }
    __syncthreads();

    // epilogue: rows [n0, n0+64) -> out[b*N+n] + bias, coalesced per b
    const int n0  = c * ROWS_PC + (int)q * QROWS;
    const int row = t & 63;
    const int bq  = t >> 6;
    const int n = n0 + row;
    if (n < N) {
        const float bv = bias[n];
        for (int b = bq; b < BATCH; b += 8)
            out[(size_t)b * N + n] = tile[row * 65 + b] + bv;
    }
}

// ---- fallback path (ws too small or N doesn't fit u16): direct atomics ----
__global__ void k_edge_scatter_direct(const float* __restrict__ in,
                                      const float* __restrict__ W3,
                                      const float* __restrict__ velocity,
                                      const int* __restrict__ I,
                                      const int* __restrict__ J,
                                      float* __restrict__ out, int N, int E) {
    const int lane = threadIdx.x & 63;
    const long wave   = (long)blockIdx.x * (blockDim.x >> 6) + (threadIdx.x >> 6);
    const long nwaves = (long)gridDim.x * (blockDim.x >> 6);
    for (long base = wave * 64; base < E; base += nwaves * 64) {
        const long e = base + lane;
        int iv = 0, jv = 0; float wvv = 0.f;
        if (e < E) { iv = I[e]; jv = J[e]; wvv = W3[e] * velocity[jv]; }
        const int cnt = (int)((E - base) < 64 ? (E - base) : 64);
        for (int k = 0; k < cnt; ++k) {
            const int   ii = __shfl(iv, k);
            const int   jj = __shfl(jv, k);
            const float wvx = __shfl(wvv, k);
            const float val = in[(size_t)lane * N + jj] * wvx;
            atomicAdd(&out[(size_t)lane * N + ii], val);
        }
    }
}

__global__ void k_add_bias(const float* __restrict__ bias, float* __restrict__ out, int N, int total) {
    int idx = blockIdx.x * blockDim.x + threadIdx.x;
    if (idx < total) out[idx] += bias[idx % N];
}

extern "C" void kernel_launch(void* const* d_in, const int* in_sizes, int n_in,
                              void* d_out, int out_size, void* d_ws, size_t ws_size,
                              hipStream_t stream) {
    const float* inputs   = (const float*)d_in[0];
    const float* W3       = (const float*)d_in[1];
    const float* bias     = (const float*)d_in[2];
    const float* velocity = (const float*)d_in[3];
    const int*   I        = (const int*)d_in[4];
    const int*   J        = (const int*)d_in[5];
    const int E = in_sizes[1];
    const int N = in_sizes[3];
    float* out = (float*)d_out;

    const size_t mat_elems = (size_t)N * BATCH;
    const int NC   = (N + ROWS_PC - 1) / ROWS_PC;   // coarse buckets
    const int nb_n = (N + 63) / 64;
    const int nb_e = (E + PCHUNK - 1) / PCHUNK;
    const int nb_g = NC * 4;                        // one block per 64-row quadrant

    // ws: in_T | part | coarse_hist | coarse_base | gcursor
    const size_t need = mat_elems * sizeof(float)
                      + (size_t)E * sizeof(ull)
                      + (size_t)(NC + (NC + 1) + NC) * sizeof(int);

    if (ws_size >= need && N <= 65535 && NC <= 256) {
        float* in_T        = (float*)d_ws;
        ull*   part        = (ull*)(in_T + mat_elems);
        int*   coarse_hist = (int*)(part + E);
        int*   coarse_base = coarse_hist + NC;
        int*   gcursor     = coarse_base + NC + 1;

        k_prep     <<<nb_n, 256, 0, stream>>>(inputs, in_T, coarse_hist, NC, N);
        k_hist     <<<nb_e, 256, 0, stream>>>(I, coarse_hist, E);
        k_scan     <<<1,    256, 0, stream>>>(coarse_hist, coarse_base, gcursor, NC);
        k_partition<<<nb_e, 256, 0, stream>>>(I, J, W3, velocity, gcursor, part, E);
        k_gather   <<<nb_g, 512, 0, stream>>>(in_T, part, coarse_base, bias, out, N);
    } else {
        hipMemsetAsync(out, 0, (size_t)out_size * sizeof(float), stream);
        const int waves_needed   = (E + 63) / 64;
        const int scatter_blocks = (waves_needed + 3) / 4;
        k_edge_scatter_direct<<<scatter_blocks, 256, 0, stream>>>(inputs, W3, velocity, I, J, out, N, E);
        k_add_bias<<<(out_size + 255) / 256, 256, 0, stream>>>(bias, out, N, out_size);
    }
}